// Round 4
// baseline (314.571 us; speedup 1.0000x reference)
//
#include <hip/hip_runtime.h>

// out[b,f] = x0[b,f] * dot(x[b,:], w) + bias[f] + x[b,f]
// B = 16384 rows, F = 2048 cols, fp32 throughout.
//
// Round 4: explicit L3 (Infinity Cache, 256 MB) residency management.
// Model fitted to rounds 0-3 FETCH_SIZE data:
//   - nt-store on out provably bypasses L3 allocation (r3: FETCH was
//     EXACTLY one array's worth -> x stayed 100% resident).
//   - nt-load prevents allocation (r3's nt x0 loads = 0% x0 hit).
// Read set x+x0 = 268 MB is 4% over the 256 MB L3. Fix: stream exactly
// 1/4 of x0 rows (the r==0 row of each wave's 4-row group) with nt loads.
// Cached set = 134 (x) + 100.6 (3/4 x0) = 235 MB < 256 MB -> deterministic
// residency, no LRU-thrash cliff. Predicted FETCH/iter: ~34 MB (the
// streamed quarter), down from 134 MB.
//
// Everything else identical to round 3: 4 rows/wave, w+bias in registers
// once per wave, 1-deep cross-row prefetch pipeline, nt stores, no LDS,
// no barriers.

#define F_DIM 2048
#define SLOTS 8   // float4 slots per lane: (F_DIM/4)/64
#define ROWS  4   // rows processed per wave

typedef float f4 __attribute__((ext_vector_type(4)));

__global__ __launch_bounds__(256) void cross_row_kernel(
    const float* __restrict__ x0,
    const float* __restrict__ x,
    const float* __restrict__ w,
    const float* __restrict__ bias,
    float* __restrict__ out)
{
    const int wave = threadIdx.x >> 6;
    const int lane = threadIdx.x & 63;
    const long long wid  = (long long)blockIdx.x * 4 + wave;
    const long long row0 = wid * ROWS;

    const f4* __restrict__ w4  = (const f4*)w;
    const f4* __restrict__ bi4 = (const f4*)bias;

    // Per-wave invariants: full w and bias rows in registers.
    f4 wr[SLOTS], br[SLOTS];
    #pragma unroll
    for (int i = 0; i < SLOTS; ++i) wr[i] = w4 [lane + 64 * i];
    #pragma unroll
    for (int i = 0; i < SLOTS; ++i) br[i] = bi4[lane + 64 * i];

    const f4* __restrict__ xbase  = (const f4*)(x  + row0 * F_DIM);
    const f4* __restrict__ x0base = (const f4*)(x0 + row0 * F_DIM);
    f4*       __restrict__ obase  = (f4*)(out + row0 * F_DIM);
    const int F4 = F_DIM / 4;  // 512 f4 per row

    f4 xa[SLOTS], x0a[SLOTS];   // current row
    f4 xb[SLOTS], x0b[SLOTS];   // prefetched next row

    // Prologue: row 0 in flight. Row 0 of each group is the STREAMED
    // quarter of x0 (nt load -> no L3 allocation).
    #pragma unroll
    for (int i = 0; i < SLOTS; ++i) xa[i] = xbase[lane + 64 * i];
    #pragma unroll
    for (int i = 0; i < SLOTS; ++i)
        x0a[i] = __builtin_nontemporal_load(&x0base[lane + 64 * i]);

    #pragma unroll
    for (int r = 0; r < ROWS; ++r) {
        // Prefetch row r+1 BEFORE the reduce. Rows 1..3: normal (caching)
        // x0 loads -> these 3/4 of x0 stay L3-resident across iterations.
        if (r + 1 < ROWS) {
            const f4* __restrict__ xn  = xbase  + (r + 1) * F4;
            const f4* __restrict__ x0n = x0base + (r + 1) * F4;
            #pragma unroll
            for (int i = 0; i < SLOTS; ++i) xb[i] = xn[lane + 64 * i];
            #pragma unroll
            for (int i = 0; i < SLOTS; ++i) x0b[i] = x0n[lane + 64 * i];
        }

        // Per-lane partial dot (32 elements), then 64-lane butterfly.
        float partial = 0.0f;
        #pragma unroll
        for (int i = 0; i < SLOTS; ++i)
            partial += xa[i][0] * wr[i][0] + xa[i][1] * wr[i][1]
                     + xa[i][2] * wr[i][2] + xa[i][3] * wr[i][3];
        #pragma unroll
        for (int off = 32; off > 0; off >>= 1)
            partial += __shfl_xor(partial, off, 64);
        const float dot = partial;

        // Epilogue: x0*dot + bias + x. nt store: out must NOT allocate in
        // L3 (proven effective in r3 -> keeps the read set resident).
        f4* __restrict__ o = obase + r * F4;
        #pragma unroll
        for (int i = 0; i < SLOTS; ++i) {
            f4 ov;
            ov[0] = x0a[i][0] * dot + (br[i][0] + xa[i][0]);
            ov[1] = x0a[i][1] * dot + (br[i][1] + xa[i][1]);
            ov[2] = x0a[i][2] * dot + (br[i][2] + xa[i][2]);
            ov[3] = x0a[i][3] * dot + (br[i][3] + xa[i][3]);
            __builtin_nontemporal_store(ov, &o[lane + 64 * i]);
        }

        // Rotate pipeline registers (statically unrolled -> pure renaming).
        #pragma unroll
        for (int i = 0; i < SLOTS; ++i) { xa[i] = xb[i]; x0a[i] = x0b[i]; }
    }
}

extern "C" void kernel_launch(void* const* d_in, const int* in_sizes, int n_in,
                              void* d_out, int out_size, void* d_ws, size_t ws_size,
                              hipStream_t stream) {
    const float* x0   = (const float*)d_in[0];
    const float* x    = (const float*)d_in[1];
    const float* w    = (const float*)d_in[2];
    const float* bias = (const float*)d_in[3];
    float* out = (float*)d_out;

    const int B = in_sizes[0] / F_DIM;          // 16384 rows
    const int blocks = B / (4 * ROWS);          // 4 waves/block * ROWS rows/wave
    cross_row_kernel<<<blocks, 256, 0, stream>>>(x0, x, w, bias, out);
}